// Round 1
// 358.122 us; speedup vs baseline: 1.0484x; 1.0484x over previous
//
#include <hip/hip_runtime.h>

// GATv2 3-layer + mean-pool + linear head, MI355X.
// R20: attn VALU diet. (1) logit = (0.6*att)·v + (0.4*att)·|v| with v computed
// in packed fp16 (v_pk_add_f16 + v_and abs + v_dot2_f32_f16): 2 VALU/ch vs 6.
// (2) self-loop folded into CSR (slot off[d]+0 written by k_scan_emit) - kills
// the special-cased self EDGE_LOGIT. (3) exact defer-max: skip the corr
// rescale when chunk max <= running max (corr==1, bit-exact skip).
// (4) prefetch next chunk's srcs one iter ahead.

#define NN 50000
#define NE 1000000
#define HID 64
#define DIN0 128
#define NG 256
#define NEG 0.2f

#define SCHUNK 1024
#define SNB ((NN + SCHUNK - 1) / SCHUNK)   // 49 blocks

typedef float f32x4 __attribute__((ext_vector_type(4)));
typedef short s8v __attribute__((ext_vector_type(8)));
typedef short s4v __attribute__((ext_vector_type(4)));
typedef __bf16 bf16x8 __attribute__((ext_vector_type(8)));
typedef _Float16 h2v __attribute__((ext_vector_type(2)));
typedef unsigned short u16;

__device__ __forceinline__ unsigned short f2bf(float f) {
    unsigned u = __float_as_uint(f);
    u = u + 0x7fffu + ((u >> 16) & 1u);   // RNE
    return (unsigned short)(u >> 16);
}
__device__ __forceinline__ float bf2f(unsigned short v) {
    return __uint_as_float(((unsigned)v) << 16);
}
__device__ __forceinline__ short split_hi(float x) {
    return (short)f2bf(x);
}
__device__ __forceinline__ short split_lo(float x, short hi) {
    return (short)f2bf(x - bf2f((unsigned short)hi));
}
__device__ __forceinline__ h2v u2h(unsigned u) { return __builtin_bit_cast(h2v, u); }
__device__ __forceinline__ unsigned h2u(h2v h) { return __builtin_bit_cast(unsigned, h); }
__device__ __forceinline__ float hx(unsigned u, int hi) {
    h2v h = __builtin_bit_cast(h2v, u);
    return (float)h[hi];
}

// ---- merged weight pre-split (all 3 layers) + zero startg/endg ----
__global__ __launch_bounds__(256) void k_wt_all(
        const float* __restrict__ Wl0, const float* __restrict__ Wr0, const float* __restrict__ Rw0,
        const float* __restrict__ Wl1, const float* __restrict__ Wr1, const float* __restrict__ Rw1,
        const float* __restrict__ Wl2, const float* __restrict__ Wr2, const float* __restrict__ Rw2,
        short* __restrict__ Ws0, short* __restrict__ Ws1, short* __restrict__ Ws2,
        int* __restrict__ startg, int* __restrict__ endg) {
    int i = blockIdx.x * 256 + threadIdx.x;
    if (i < 2 * NG) {
        if (i < NG) startg[i] = 0; else endg[i - NG] = 0;
    }
    const int L0N = 3 * HID * DIN0;
    const int L1N = 3 * HID * HID;
    if (i >= L0N + 2 * L1N) return;
    const float* Wm; short* Ws; int din, local;
    if (i < L0N) {
        local = i; din = DIN0; Ws = Ws0;
        int m = local / (DIN0 * HID);
        Wm = (m == 0) ? Wl0 : (m == 1) ? Wr0 : Rw0;
    } else if (i < L0N + L1N) {
        local = i - L0N; din = HID; Ws = Ws1;
        int m = local / (HID * HID);
        Wm = (m == 0) ? Wl1 : (m == 1) ? Wr1 : Rw1;
    } else {
        local = i - L0N - L1N; din = HID; Ws = Ws2;
        int m = local / (HID * HID);
        Wm = (m == 0) ? Wl2 : (m == 1) ? Wr2 : Rw2;
    }
    int m = local / (din * HID);
    int r = local - m * (din * HID);
    int c = r / din, k = r - c * din;
    float w = Wm[c * din + k];
    short hi = split_hi(w);
    short lo = split_lo(w, hi);
    Ws[(((m * 2 + 0) * HID + c) * din) + k] = hi;
    Ws[(((m * 2 + 1) * HID + c) * din) + k] = lo;
}

// ---- graph bounds + zero hist slices ----
__global__ void k_bounds(const int* __restrict__ batch,
                         int* __restrict__ startg, int* __restrict__ endg,
                         int* __restrict__ cnt8) {
    int i = blockIdx.x * 256 + threadIdx.x;
    if (i >= NN) return;
#pragma unroll
    for (int g = 0; g < 8; g++) cnt8[g * NN + i] = 0;
    int g = batch[i];
    if (i == 0 || batch[i - 1] != g) startg[g] = i;
    if (i == NN - 1 || batch[i + 1] != g) endg[g] = i + 1;
}

// ---- XCD-sliced histogram; atomic return = rank within (slice,dst) ----
__global__ __launch_bounds__(256) void k_hist8(const int* __restrict__ edst,
                                               int* __restrict__ cnt8,
                                               u16* __restrict__ rank) {
    int* mycnt = cnt8 + (blockIdx.x & 7) * NN;
    for (int e = blockIdx.x * 256 + threadIdx.x; e < NE; e += 512 * 256) {
        int r = atomicAdd(&mycnt[edst[e]], 1);
        rank[e] = (u16)r;
    }
}

// ---- per-dst: slice-exclusive prefixes (in place) + total ----
// R20: prefixes start at 1 - slot 0 of each dst is the self-loop edge.
__global__ void k_hist_red(int* __restrict__ cnt8, int* __restrict__ cnt) {
    int i = blockIdx.x * 256 + threadIdx.x;
    if (i >= NN) return;
    int s = 1;                               // reserve slot 0 for self-loop
#pragma unroll
    for (int g = 0; g < 8; g++) {
        int t = cnt8[g * NN + i];
        cnt8[g * NN + i] = s;
        s += t;
    }
    cnt[i] = s;                              // deg + 1 (incl self)
}

__global__ __launch_bounds__(256) void k_scan_part(const int* __restrict__ cnt,
                                                   int* __restrict__ part) {
    __shared__ int ws[4];
    int b = blockIdx.x, t = threadIdx.x;
    int i0 = b * SCHUNK + t * 4;
    int s = 0;
#pragma unroll
    for (int j = 0; j < 4; j++) {
        int i = i0 + j;
        if (i < NN) s += cnt[i];
    }
#pragma unroll
    for (int o = 32; o; o >>= 1) s += __shfl_xor(s, o, 64);
    if ((t & 63) == 0) ws[t >> 6] = s;
    __syncthreads();
    if (t == 0) part[b] = ws[0] + ws[1] + ws[2] + ws[3];
}

__global__ void k_scan_small(const int* __restrict__ part, int* __restrict__ partScan) {
    __shared__ int sh[SNB];
    int t = threadIdx.x;
    if (t < SNB) sh[t] = part[t];
    __syncthreads();
    if (t < SNB) {
        int s = 0;
        for (int i = 0; i < t; i++) s += sh[i];
        partScan[t] = s;
    }
}

// R20: also writes the self-loop src (srcs[off[i]] = i) - runs before scatter.
__global__ __launch_bounds__(256) void k_scan_emit(const int* __restrict__ cnt,
                                                   const int* __restrict__ partScan,
                                                   int* __restrict__ off,
                                                   u16* __restrict__ srcs) {
    __shared__ int tsum[256];
    int b = blockIdx.x, t = threadIdx.x;
    int i0 = b * SCHUNK + t * 4;
    int e[4], p[4];
    int s = 0;
#pragma unroll
    for (int j = 0; j < 4; j++) {
        int i = i0 + j;
        e[j] = (i < NN) ? cnt[i] : 0;
        p[j] = s;
        s += e[j];
    }
    tsum[t] = s;
    __syncthreads();
    for (int d = 1; d < 256; d <<= 1) {
        int v = (t >= d) ? tsum[t - d] : 0;
        __syncthreads();
        tsum[t] += v;
        __syncthreads();
    }
    int base = partScan[b] + ((t == 0) ? 0 : tsum[t - 1]);
#pragma unroll
    for (int j = 0; j < 4; j++) {
        int i = i0 + j;
        if (i < NN) {
            int v = base + p[j];
            off[i] = v;
            srcs[v] = (u16)i;                // self-loop edge in slot 0
            if (i == NN - 1) off[NN] = v + e[j];
        }
    }
}

// ---- atomic-free scatter: pos = off[d] + sliceBase[slice][d] + rank[e] ----
__global__ __launch_bounds__(256) void k_scatter_rank(
        const int* __restrict__ esrc, const int* __restrict__ edst,
        const int* __restrict__ off, const int* __restrict__ cnt8,
        const u16* __restrict__ rank, u16* __restrict__ srcs) {
    int e = blockIdx.x * 256 + threadIdx.x;
    if (e >= NE) return;
    int d = edst[e];
    int slice = (e >> 8) & 7;               // matches k_hist8's block mapping
    int pos = off[d] + cnt8[slice * NN + d] + (int)rank[e];
    srcs[pos] = (u16)esrc[e];
}

// ---- fused node GEMMs via split-precision bf16 MFMA; xl output as fp16 ----
template <int DIN, bool RELU>
__global__ __launch_bounds__(256, 3) void k_gemm(
        const float* __restrict__ xin, const short* __restrict__ Ws,
        const float* __restrict__ bvec, const float* __restrict__ rb,
        _Float16* __restrict__ xl16, float* __restrict__ xr, float* __restrict__ acc) {
    constexpr int LROW = 40;
    __shared__ short lds[20480];            // 40 KB
    short* xhi = lds;
    short* xlo = lds + 2560;

    const int tid = threadIdx.x;
    const int w = tid >> 6;
    const int lane = tid & 63;
    const int col = lane & 15;
    const int quad = lane >> 4;
    const int nb0 = blockIdx.x * 64;

    f32x4 d[3][4];
#pragma unroll
    for (int m = 0; m < 3; m++)
#pragma unroll
        for (int ct = 0; ct < 4; ct++) d[m][ct] = (f32x4){0.f, 0.f, 0.f, 0.f};

    for (int c0 = 0; c0 < DIN; c0 += 32) {
        if (c0) __syncthreads();
        for (int u = tid; u < 512; u += 256) {
            int row = u >> 3, kq = u & 7;
            int n = nb0 + row;
            float4 v = make_float4(0.f, 0.f, 0.f, 0.f);
            if (n < NN) {
                v = *(const float4*)&xin[(size_t)n * DIN + c0 + 4 * kq];
                if (RELU) {
                    v.x = fmaxf(v.x, 0.f); v.y = fmaxf(v.y, 0.f);
                    v.z = fmaxf(v.z, 0.f); v.w = fmaxf(v.w, 0.f);
                }
            }
            s4v h, l;
            short h0 = split_hi(v.x), l0 = split_lo(v.x, h0);
            short h1 = split_hi(v.y), l1 = split_lo(v.y, h1);
            short h2 = split_hi(v.z), l2 = split_lo(v.z, h2);
            short h3 = split_hi(v.w), l3 = split_lo(v.w, h3);
            h[0] = h0; h[1] = h1; h[2] = h2; h[3] = h3;
            l[0] = l0; l[1] = l1; l[2] = l2; l[3] = l3;
            *(s4v*)&xhi[row * LROW + 4 * kq] = h;
            *(s4v*)&xlo[row * LROW + 4 * kq] = l;
        }
        for (int u = tid; u < 1536; u += 256) {
            int mp = u >> 8;
            int r = u & 255;
            int c = r >> 2, q = r & 3;
            s8v v = *(const s8v*)&Ws[((mp * HID + c) * DIN) + c0 + 8 * q];
            *(s8v*)&lds[5120 + mp * 2560 + c * LROW + 8 * q] = v;
        }
        __syncthreads();

        bf16x8 a_h = __builtin_bit_cast(bf16x8,
            *(const s8v*)&xhi[(w * 16 + col) * LROW + quad * 8]);
        bf16x8 a_l = __builtin_bit_cast(bf16x8,
            *(const s8v*)&xlo[(w * 16 + col) * LROW + quad * 8]);

#pragma unroll
        for (int m = 0; m < 3; m++) {
#pragma unroll
            for (int ct = 0; ct < 4; ct++) {
                bf16x8 b_h = __builtin_bit_cast(bf16x8,
                    *(const s8v*)&lds[5120 + (m * 2 + 0) * 2560 + (ct * 16 + col) * LROW + quad * 8]);
                bf16x8 b_l = __builtin_bit_cast(bf16x8,
                    *(const s8v*)&lds[5120 + (m * 2 + 1) * 2560 + (ct * 16 + col) * LROW + quad * 8]);
                d[m][ct] = __builtin_amdgcn_mfma_f32_16x16x32_bf16(a_h, b_h, d[m][ct], 0, 0, 0);
                d[m][ct] = __builtin_amdgcn_mfma_f32_16x16x32_bf16(a_h, b_l, d[m][ct], 0, 0, 0);
                d[m][ct] = __builtin_amdgcn_mfma_f32_16x16x32_bf16(a_l, b_h, d[m][ct], 0, 0, 0);
            }
        }
    }

#pragma unroll
    for (int r = 0; r < 4; r++) {
        int n = nb0 + w * 16 + quad * 4 + r;
        if (n >= NN) continue;
        size_t base = (size_t)n * HID;
#pragma unroll
        for (int ct = 0; ct < 4; ct++) {
            int c = ct * 16 + col;
            xl16[base + c] = (_Float16)d[0][ct][r];
            xr[base + c] = d[1][ct][r];
            acc[base + c] = d[2][ct][r] + bvec[c] + rb[c];
        }
    }
}

// ---- fused per-dst attention: 16 edges/iter (2 per e-slot) x 8 channels ----
// R20: logit = dot(0.6*att, v) + dot(0.4*att, |v|) in packed fp16 (v_dot2),
// self-loop comes from CSR slot 0, exact defer-max, srcs prefetch.
__global__ __launch_bounds__(256) void k_attn_dst(
        const int* __restrict__ off, const u16* __restrict__ srcs,
        const _Float16* __restrict__ xl16, const float* __restrict__ xr,
        const float* __restrict__ att, float* __restrict__ acc) {
    const int lane = threadIdx.x & 63;
    const int d = blockIdx.x * 4 + (threadIdx.x >> 6);
    if (d >= NN) return;
    const int e = lane >> 3;
    const int cg = lane & 7;

    const float4* xr4 = (const float4*)&xr[(size_t)d * HID + 8 * cg];
    float4 xra = xr4[0], xrb = xr4[1];
    const float4* at4 = (const float4*)&att[8 * cg];
    float4 ata = at4[0], atb = at4[1];
    // pre-packed fp16: xr and pre-scaled att (leaky(v)*a = 0.6a*v + 0.4a*|v|)
    h2v xh0 = {(_Float16)xra.x, (_Float16)xra.y};
    h2v xh1 = {(_Float16)xra.z, (_Float16)xra.w};
    h2v xh2 = {(_Float16)xrb.x, (_Float16)xrb.y};
    h2v xh3 = {(_Float16)xrb.z, (_Float16)xrb.w};
    h2v a6h0 = {(_Float16)(0.6f * ata.x), (_Float16)(0.6f * ata.y)};
    h2v a6h1 = {(_Float16)(0.6f * ata.z), (_Float16)(0.6f * ata.w)};
    h2v a6h2 = {(_Float16)(0.6f * atb.x), (_Float16)(0.6f * atb.y)};
    h2v a6h3 = {(_Float16)(0.6f * atb.z), (_Float16)(0.6f * atb.w)};
    h2v a4h0 = {(_Float16)(0.4f * ata.x), (_Float16)(0.4f * ata.y)};
    h2v a4h1 = {(_Float16)(0.4f * ata.z), (_Float16)(0.4f * ata.w)};
    h2v a4h2 = {(_Float16)(0.4f * atb.x), (_Float16)(0.4f * atb.y)};
    h2v a4h3 = {(_Float16)(0.4f * atb.z), (_Float16)(0.4f * atb.w)};

#define EDGE_LOGIT(S, U, T)                                                    \
    {                                                                          \
        U = *(const uint4*)&xl16[(size_t)(S) * HID + 8 * cg];                  \
        h2v _v; unsigned _a; float _ps;                                        \
        _v = u2h(U.x) + xh0; _a = h2u(_v) & 0x7FFF7FFFu;                       \
        _ps = __builtin_amdgcn_fdot2(a6h0, _v, 0.f, false);                    \
        _ps = __builtin_amdgcn_fdot2(a4h0, u2h(_a), _ps, false);               \
        _v = u2h(U.y) + xh1; _a = h2u(_v) & 0x7FFF7FFFu;                       \
        _ps = __builtin_amdgcn_fdot2(a6h1, _v, _ps, false);                    \
        _ps = __builtin_amdgcn_fdot2(a4h1, u2h(_a), _ps, false);               \
        _v = u2h(U.z) + xh2; _a = h2u(_v) & 0x7FFF7FFFu;                       \
        _ps = __builtin_amdgcn_fdot2(a6h2, _v, _ps, false);                    \
        _ps = __builtin_amdgcn_fdot2(a4h2, u2h(_a), _ps, false);               \
        _v = u2h(U.w) + xh3; _a = h2u(_v) & 0x7FFF7FFFu;                       \
        _ps = __builtin_amdgcn_fdot2(a6h3, _v, _ps, false);                    \
        _ps = __builtin_amdgcn_fdot2(a4h3, u2h(_a), _ps, false);               \
        _ps += __shfl_xor(_ps, 1, 64);                                         \
        _ps += __shfl_xor(_ps, 2, 64);                                         \
        _ps += __shfl_xor(_ps, 4, 64);                                         \
        T = _ps;                                                               \
    }

#define ACC8(OP)                                                               \
    oA.x = OP(oA.x, hx(U0.x, 0), hx(U1.x, 0));                                 \
    oA.y = OP(oA.y, hx(U0.x, 1), hx(U1.x, 1));                                 \
    oA.z = OP(oA.z, hx(U0.y, 0), hx(U1.y, 0));                                 \
    oA.w = OP(oA.w, hx(U0.y, 1), hx(U1.y, 1));                                 \
    oB.x = OP(oB.x, hx(U0.z, 0), hx(U1.z, 0));                                 \
    oB.y = OP(oB.y, hx(U0.z, 1), hx(U1.z, 1));                                 \
    oB.z = OP(oB.z, hx(U0.w, 0), hx(U1.w, 0));                                 \
    oB.w = OP(oB.w, hx(U0.w, 1), hx(U1.w, 1));
#define OP_RS(o, x0, x1) fmaf(o, corr, fmaf(p0, x0, p1 * (x1)))
#define OP_NR(o, x0, x1) fmaf(p0, x0, fmaf(p1, (x1), o))

    float m = -INFINITY, l = 0.f;
    float4 oA = make_float4(0.f, 0.f, 0.f, 0.f);
    float4 oB = make_float4(0.f, 0.f, 0.f, 0.f);

    const int lo = off[d], deg = off[d + 1] - lo;   // includes self-loop
    int sv = 0;
    if (lane < 16) sv = (int)srcs[lo + min(lane, deg - 1)];
    for (int base = 0; base < deg; base += 16) {
        int svc = sv;
        if (base + 16 < deg && lane < 16)
            sv = (int)srcs[lo + min(base + 16 + lane, deg - 1)];   // prefetch
        int s0 = __shfl(svc, e, 64);
        int s1 = __shfl(svc, e + 8, 64);

        uint4 U0, U1; float t0, t1;
        EDGE_LOGIT(s0, U0, t0);
        EDGE_LOGIT(s1, U1, t1);
        if (base + e >= deg) t0 = -INFINITY;
        if (base + 8 + e >= deg) t1 = -INFINITY;

        float cm = fmaxf(t0, t1);
        cm = fmaxf(cm, __shfl_xor(cm, 8, 64));
        cm = fmaxf(cm, __shfl_xor(cm, 16, 64));
        cm = fmaxf(cm, __shfl_xor(cm, 32, 64));
        if (cm > m) {                      // wave-uniform; first iter always
            float corr = __expf(m - cm);   // exp(-inf)=0 on first iter
            float p0 = __expf(t0 - cm);
            float p1 = __expf(t1 - cm);
            m = cm;
            l = fmaf(l, corr, p0 + p1);
            ACC8(OP_RS)
        } else {                           // corr == 1 exactly -> skip rescale
            float p0 = __expf(t0 - m);
            float p1 = __expf(t1 - m);
            l += p0 + p1;
            ACC8(OP_NR)
        }
    }
#undef EDGE_LOGIT
#undef ACC8
#undef OP_RS
#undef OP_NR

#pragma unroll
    for (int w = 8; w <= 32; w <<= 1) {
        l    += __shfl_xor(l, w, 64);
        oA.x += __shfl_xor(oA.x, w, 64); oA.y += __shfl_xor(oA.y, w, 64);
        oA.z += __shfl_xor(oA.z, w, 64); oA.w += __shfl_xor(oA.w, w, 64);
        oB.x += __shfl_xor(oB.x, w, 64); oB.y += __shfl_xor(oB.y, w, 64);
        oB.z += __shfl_xor(oB.z, w, 64); oB.w += __shfl_xor(oB.w, w, 64);
    }

    if (e == 0) {
        float inv = 1.f / l;
        float4* a4 = (float4*)&acc[(size_t)d * HID + 8 * cg];
        float4 c0 = a4[0], c1 = a4[1];
        c0.x += oA.x * inv; c0.y += oA.y * inv;
        c0.z += oA.z * inv; c0.w += oA.w * inv;
        c1.x += oB.x * inv; c1.y += oB.y * inv;
        c1.z += oB.z * inv; c1.w += oB.w * inv;
        a4[0] = c0; a4[1] = c1;
    }
}

// ---- fused mean-pool + head ----
__global__ __launch_bounds__(512) void k_pool_final(
        const float* __restrict__ acc,
        const int* __restrict__ startg, const int* __restrict__ endg,
        const float* __restrict__ Wf, const float* __restrict__ bf_,
        float* __restrict__ out) {
    __shared__ float red[8][HID];
    const int g = blockIdx.x;
    const int c = threadIdx.x & 63;
    const int j = threadIdx.x >> 6;
    const int s = startg[g], epos = endg[g];

    float sum = 0.f;
    for (int n = s + j; n < epos; n += 8)
        sum += acc[(size_t)n * HID + c];
    red[j][c] = sum;
    __syncthreads();

    if (threadIdx.x < HID) {
        float tot = 0.f;
#pragma unroll
        for (int w = 0; w < 8; w++) tot += red[w][c];
        float cntf = (float)(epos - s);
        float v = tot / fmaxf(cntf, 1.f) * Wf[c];
#pragma unroll
        for (int o = 32; o; o >>= 1) v += __shfl_xor(v, o, 64);
        if (c == 0) out[g] = v + bf_[0];
    }
}

extern "C" void kernel_launch(void* const* d_in, const int* in_sizes, int n_in,
                              void* d_out, int out_size, void* d_ws, size_t ws_size,
                              hipStream_t stream) {
    const float* x   = (const float*)d_in[0];
    const int* eidx  = (const int*)d_in[1];
    const int* batch = (const int*)d_in[2];
    const int* esrc = eidx;
    const int* edst = eidx + NE;
    const float* Wf  = (const float*)d_in[21];
    const float* bfb = (const float*)d_in[22];

    float* wsf = (float*)d_ws;
    const size_t NN64 = (size_t)NN * HID;
    _Float16* xl16 = (_Float16*)wsf;                // NN64 halfs
    float* xr     = wsf + NN64;
    float* acc0   = xr + NN64;
    float* acc1   = acc0 + NN64;
    short* Ws0    = (short*)(acc1 + NN64);
    short* Ws1    = Ws0 + 2 * 3 * HID * DIN0;
    short* Ws2    = Ws1 + 2 * 3 * HID * HID;
    int*   ccnt   = (int*)(Ws2 + 2 * 3 * HID * HID);
    int*   startg = ccnt + NN;
    int*   endg   = startg + NG;
    int*   off    = endg + NG;
    int*   part   = off + NN + 1;
    int*   partSc = part + SNB;
    int*   cnt8   = partSc + SNB;                   // 8*NN
    u16*   rank   = (u16*)(cnt8 + 8 * NN);          // NE u16
    u16*   srcs   = rank + NE;                      // NE + NN u16 (self-loops)

    k_wt_all<<<(3 * HID * DIN0 + 2 * 3 * HID * HID + 255) / 256, 256, 0, stream>>>(
        (const float*)d_in[3], (const float*)d_in[4], (const float*)d_in[7],
        (const float*)d_in[9], (const float*)d_in[10], (const float*)d_in[13],
        (const float*)d_in[15], (const float*)d_in[16], (const float*)d_in[19],
        Ws0, Ws1, Ws2, startg, endg);
    k_bounds<<<(NN + 255) / 256, 256, 0, stream>>>(batch, startg, endg, cnt8);

    k_hist8<<<512, 256, 0, stream>>>(edst, cnt8, rank);
    k_hist_red<<<(NN + 255) / 256, 256, 0, stream>>>(cnt8, ccnt);
    k_scan_part<<<SNB, 256, 0, stream>>>(ccnt, part);
    k_scan_small<<<1, 64, 0, stream>>>(part, partSc);
    k_scan_emit<<<SNB, 256, 0, stream>>>(ccnt, partSc, off, srcs);
    k_scatter_rank<<<(NE + 255) / 256, 256, 0, stream>>>(esrc, edst, off, cnt8, rank, srcs);

    const short* Wss[3] = {Ws0, Ws1, Ws2};
    float* accs[4] = {acc0, acc0, acc1, acc0};  // out of layer L = accs[L+1]
    const int gemm_grid = (NN + 63) / 64;
    for (int L = 0; L < 3; L++) {
        const float* att = (const float*)d_in[3 + L * 6 + 2];
        const float* b   = (const float*)d_in[3 + L * 6 + 3];
        const float* Rb  = (const float*)d_in[3 + L * 6 + 5];
        float* accOut = accs[L + 1];

        if (L == 0)
            k_gemm<DIN0, false><<<gemm_grid, 256, 0, stream>>>(
                x, Wss[0], b, Rb, xl16, xr, accOut);
        else
            k_gemm<HID, true><<<gemm_grid, 256, 0, stream>>>(
                accs[L], Wss[L], b, Rb, xl16, xr, accOut);

        k_attn_dst<<<(NN + 3) / 4, 256, 0, stream>>>(off, srcs, xl16, xr, att, accOut);
    }

    k_pool_final<<<NG, 512, 0, stream>>>(accs[3], startg, endg, Wf, bfb, (float*)d_out);
}

// Round 2
// 347.719 us; speedup vs baseline: 1.0797x; 1.0299x over previous
//
#include <hip/hip_runtime.h>

// GATv2 3-layer + mean-pool + linear head, MI355X.
// R21: attn round 2. (1) PV accumulation via v_dot2_f32_f16: p packed to fp16
// (cvt_pkrtz) + x pairs built with v_perm_b32 from the already-fp16 gathers -
// 32 ops vs 64 (cvt+fma) per 4 edges. (2) chunk=32 (4 edges/e-slot): 4
// independent gathers in flight, one softmax epilogue per dst (99% of dsts).
// (3) setup hoisted: xr stored fp16 by k_gemm; 0.6*att/0.4*att fp16 tables
// prebuilt in k_wt_all. Self-loop-in-CSR, exact defer-max, prefetch kept.

#define NN 50000
#define NE 1000000
#define HID 64
#define DIN0 128
#define NG 256
#define NEG 0.2f

#define SCHUNK 1024
#define SNB ((NN + SCHUNK - 1) / SCHUNK)   // 49 blocks

typedef float f32x4 __attribute__((ext_vector_type(4)));
typedef short s8v __attribute__((ext_vector_type(8)));
typedef short s4v __attribute__((ext_vector_type(4)));
typedef __bf16 bf16x8 __attribute__((ext_vector_type(8)));
typedef _Float16 h2v __attribute__((ext_vector_type(2)));
typedef unsigned short u16;

__device__ __forceinline__ unsigned short f2bf(float f) {
    unsigned u = __float_as_uint(f);
    u = u + 0x7fffu + ((u >> 16) & 1u);   // RNE
    return (unsigned short)(u >> 16);
}
__device__ __forceinline__ float bf2f(unsigned short v) {
    return __uint_as_float(((unsigned)v) << 16);
}
__device__ __forceinline__ short split_hi(float x) {
    return (short)f2bf(x);
}
__device__ __forceinline__ short split_lo(float x, short hi) {
    return (short)f2bf(x - bf2f((unsigned short)hi));
}
__device__ __forceinline__ h2v u2h(unsigned u) { return __builtin_bit_cast(h2v, u); }
__device__ __forceinline__ unsigned h2u(h2v h) { return __builtin_bit_cast(unsigned, h); }
// (b.lo16 << 16) | a.lo16  and  (b.hi16 << 16) | a.hi16  - one v_perm_b32 each
__device__ __forceinline__ h2v pklo(unsigned a, unsigned b) {
    return u2h(__builtin_amdgcn_perm(b, a, 0x05040100u));
}
__device__ __forceinline__ h2v pkhi(unsigned a, unsigned b) {
    return u2h(__builtin_amdgcn_perm(b, a, 0x07060302u));
}

// ---- merged weight pre-split (all 3 layers) + att fp16 tables + zero bounds ----
__global__ __launch_bounds__(256) void k_wt_all(
        const float* __restrict__ Wl0, const float* __restrict__ Wr0, const float* __restrict__ Rw0,
        const float* __restrict__ Wl1, const float* __restrict__ Wr1, const float* __restrict__ Rw1,
        const float* __restrict__ Wl2, const float* __restrict__ Wr2, const float* __restrict__ Rw2,
        const float* __restrict__ att0, const float* __restrict__ att1, const float* __restrict__ att2,
        short* __restrict__ Ws0, short* __restrict__ Ws1, short* __restrict__ Ws2,
        _Float16* __restrict__ attp,
        int* __restrict__ startg, int* __restrict__ endg) {
    int i = blockIdx.x * 256 + threadIdx.x;
    if (i < 2 * NG) {
        if (i < NG) startg[i] = 0; else endg[i - NG] = 0;
    }
    if (i < 3 * HID) {   // leaky(v)*a = 0.6a*v + 0.4a*|v|; pre-scale in fp16
        int L = i >> 6, c = i & 63;
        const float* at = (L == 0) ? att0 : (L == 1) ? att1 : att2;
        float a = at[c];
        attp[L * 2 * HID + c] = (_Float16)(0.6f * a);
        attp[L * 2 * HID + HID + c] = (_Float16)(0.4f * a);
    }
    const int L0N = 3 * HID * DIN0;
    const int L1N = 3 * HID * HID;
    if (i >= L0N + 2 * L1N) return;
    const float* Wm; short* Ws; int din, local;
    if (i < L0N) {
        local = i; din = DIN0; Ws = Ws0;
        int m = local / (DIN0 * HID);
        Wm = (m == 0) ? Wl0 : (m == 1) ? Wr0 : Rw0;
    } else if (i < L0N + L1N) {
        local = i - L0N; din = HID; Ws = Ws1;
        int m = local / (HID * HID);
        Wm = (m == 0) ? Wl1 : (m == 1) ? Wr1 : Rw1;
    } else {
        local = i - L0N - L1N; din = HID; Ws = Ws2;
        int m = local / (HID * HID);
        Wm = (m == 0) ? Wl2 : (m == 1) ? Wr2 : Rw2;
    }
    int m = local / (din * HID);
    int r = local - m * (din * HID);
    int c = r / din, k = r - c * din;
    float w = Wm[c * din + k];
    short hi = split_hi(w);
    short lo = split_lo(w, hi);
    Ws[(((m * 2 + 0) * HID + c) * din) + k] = hi;
    Ws[(((m * 2 + 1) * HID + c) * din) + k] = lo;
}

// ---- graph bounds + zero hist slices ----
__global__ void k_bounds(const int* __restrict__ batch,
                         int* __restrict__ startg, int* __restrict__ endg,
                         int* __restrict__ cnt8) {
    int i = blockIdx.x * 256 + threadIdx.x;
    if (i >= NN) return;
#pragma unroll
    for (int g = 0; g < 8; g++) cnt8[g * NN + i] = 0;
    int g = batch[i];
    if (i == 0 || batch[i - 1] != g) startg[g] = i;
    if (i == NN - 1 || batch[i + 1] != g) endg[g] = i + 1;
}

// ---- XCD-sliced histogram; atomic return = rank within (slice,dst) ----
__global__ __launch_bounds__(256) void k_hist8(const int* __restrict__ edst,
                                               int* __restrict__ cnt8,
                                               u16* __restrict__ rank) {
    int* mycnt = cnt8 + (blockIdx.x & 7) * NN;
    for (int e = blockIdx.x * 256 + threadIdx.x; e < NE; e += 512 * 256) {
        int r = atomicAdd(&mycnt[edst[e]], 1);
        rank[e] = (u16)r;
    }
}

// ---- per-dst: slice-exclusive prefixes (in place) + total ----
// prefixes start at 1 - slot 0 of each dst is the self-loop edge.
__global__ void k_hist_red(int* __restrict__ cnt8, int* __restrict__ cnt) {
    int i = blockIdx.x * 256 + threadIdx.x;
    if (i >= NN) return;
    int s = 1;                               // reserve slot 0 for self-loop
#pragma unroll
    for (int g = 0; g < 8; g++) {
        int t = cnt8[g * NN + i];
        cnt8[g * NN + i] = s;
        s += t;
    }
    cnt[i] = s;                              // deg + 1 (incl self)
}

__global__ __launch_bounds__(256) void k_scan_part(const int* __restrict__ cnt,
                                                   int* __restrict__ part) {
    __shared__ int ws[4];
    int b = blockIdx.x, t = threadIdx.x;
    int i0 = b * SCHUNK + t * 4;
    int s = 0;
#pragma unroll
    for (int j = 0; j < 4; j++) {
        int i = i0 + j;
        if (i < NN) s += cnt[i];
    }
#pragma unroll
    for (int o = 32; o; o >>= 1) s += __shfl_xor(s, o, 64);
    if ((t & 63) == 0) ws[t >> 6] = s;
    __syncthreads();
    if (t == 0) part[b] = ws[0] + ws[1] + ws[2] + ws[3];
}

__global__ void k_scan_small(const int* __restrict__ part, int* __restrict__ partScan) {
    __shared__ int sh[SNB];
    int t = threadIdx.x;
    if (t < SNB) sh[t] = part[t];
    __syncthreads();
    if (t < SNB) {
        int s = 0;
        for (int i = 0; i < t; i++) s += sh[i];
        partScan[t] = s;
    }
}

// also writes the self-loop src (srcs[off[i]] = i) - runs before scatter.
__global__ __launch_bounds__(256) void k_scan_emit(const int* __restrict__ cnt,
                                                   const int* __restrict__ partScan,
                                                   int* __restrict__ off,
                                                   u16* __restrict__ srcs) {
    __shared__ int tsum[256];
    int b = blockIdx.x, t = threadIdx.x;
    int i0 = b * SCHUNK + t * 4;
    int e[4], p[4];
    int s = 0;
#pragma unroll
    for (int j = 0; j < 4; j++) {
        int i = i0 + j;
        e[j] = (i < NN) ? cnt[i] : 0;
        p[j] = s;
        s += e[j];
    }
    tsum[t] = s;
    __syncthreads();
    for (int d = 1; d < 256; d <<= 1) {
        int v = (t >= d) ? tsum[t - d] : 0;
        __syncthreads();
        tsum[t] += v;
        __syncthreads();
    }
    int base = partScan[b] + ((t == 0) ? 0 : tsum[t - 1]);
#pragma unroll
    for (int j = 0; j < 4; j++) {
        int i = i0 + j;
        if (i < NN) {
            int v = base + p[j];
            off[i] = v;
            srcs[v] = (u16)i;                // self-loop edge in slot 0
            if (i == NN - 1) off[NN] = v + e[j];
        }
    }
}

// ---- atomic-free scatter: pos = off[d] + sliceBase[slice][d] + rank[e] ----
__global__ __launch_bounds__(256) void k_scatter_rank(
        const int* __restrict__ esrc, const int* __restrict__ edst,
        const int* __restrict__ off, const int* __restrict__ cnt8,
        const u16* __restrict__ rank, u16* __restrict__ srcs) {
    int e = blockIdx.x * 256 + threadIdx.x;
    if (e >= NE) return;
    int d = edst[e];
    int slice = (e >> 8) & 7;               // matches k_hist8's block mapping
    int pos = off[d] + cnt8[slice * NN + d] + (int)rank[e];
    srcs[pos] = (u16)esrc[e];
}

// ---- fused node GEMMs via split-precision bf16 MFMA; xl,xr output as fp16 ----
template <int DIN, bool RELU>
__global__ __launch_bounds__(256, 3) void k_gemm(
        const float* __restrict__ xin, const short* __restrict__ Ws,
        const float* __restrict__ bvec, const float* __restrict__ rb,
        _Float16* __restrict__ xl16, _Float16* __restrict__ xr16, float* __restrict__ acc) {
    constexpr int LROW = 40;
    __shared__ short lds[20480];            // 40 KB
    short* xhi = lds;
    short* xlo = lds + 2560;

    const int tid = threadIdx.x;
    const int w = tid >> 6;
    const int lane = tid & 63;
    const int col = lane & 15;
    const int quad = lane >> 4;
    const int nb0 = blockIdx.x * 64;

    f32x4 d[3][4];
#pragma unroll
    for (int m = 0; m < 3; m++)
#pragma unroll
        for (int ct = 0; ct < 4; ct++) d[m][ct] = (f32x4){0.f, 0.f, 0.f, 0.f};

    for (int c0 = 0; c0 < DIN; c0 += 32) {
        if (c0) __syncthreads();
        for (int u = tid; u < 512; u += 256) {
            int row = u >> 3, kq = u & 7;
            int n = nb0 + row;
            float4 v = make_float4(0.f, 0.f, 0.f, 0.f);
            if (n < NN) {
                v = *(const float4*)&xin[(size_t)n * DIN + c0 + 4 * kq];
                if (RELU) {
                    v.x = fmaxf(v.x, 0.f); v.y = fmaxf(v.y, 0.f);
                    v.z = fmaxf(v.z, 0.f); v.w = fmaxf(v.w, 0.f);
                }
            }
            s4v h, l;
            short h0 = split_hi(v.x), l0 = split_lo(v.x, h0);
            short h1 = split_hi(v.y), l1 = split_lo(v.y, h1);
            short h2 = split_hi(v.z), l2 = split_lo(v.z, h2);
            short h3 = split_hi(v.w), l3 = split_lo(v.w, h3);
            h[0] = h0; h[1] = h1; h[2] = h2; h[3] = h3;
            l[0] = l0; l[1] = l1; l[2] = l2; l[3] = l3;
            *(s4v*)&xhi[row * LROW + 4 * kq] = h;
            *(s4v*)&xlo[row * LROW + 4 * kq] = l;
        }
        for (int u = tid; u < 1536; u += 256) {
            int mp = u >> 8;
            int r = u & 255;
            int c = r >> 2, q = r & 3;
            s8v v = *(const s8v*)&Ws[((mp * HID + c) * DIN) + c0 + 8 * q];
            *(s8v*)&lds[5120 + mp * 2560 + c * LROW + 8 * q] = v;
        }
        __syncthreads();

        bf16x8 a_h = __builtin_bit_cast(bf16x8,
            *(const s8v*)&xhi[(w * 16 + col) * LROW + quad * 8]);
        bf16x8 a_l = __builtin_bit_cast(bf16x8,
            *(const s8v*)&xlo[(w * 16 + col) * LROW + quad * 8]);

#pragma unroll
        for (int m = 0; m < 3; m++) {
#pragma unroll
            for (int ct = 0; ct < 4; ct++) {
                bf16x8 b_h = __builtin_bit_cast(bf16x8,
                    *(const s8v*)&lds[5120 + (m * 2 + 0) * 2560 + (ct * 16 + col) * LROW + quad * 8]);
                bf16x8 b_l = __builtin_bit_cast(bf16x8,
                    *(const s8v*)&lds[5120 + (m * 2 + 1) * 2560 + (ct * 16 + col) * LROW + quad * 8]);
                d[m][ct] = __builtin_amdgcn_mfma_f32_16x16x32_bf16(a_h, b_h, d[m][ct], 0, 0, 0);
                d[m][ct] = __builtin_amdgcn_mfma_f32_16x16x32_bf16(a_h, b_l, d[m][ct], 0, 0, 0);
                d[m][ct] = __builtin_amdgcn_mfma_f32_16x16x32_bf16(a_l, b_h, d[m][ct], 0, 0, 0);
            }
        }
    }

#pragma unroll
    for (int r = 0; r < 4; r++) {
        int n = nb0 + w * 16 + quad * 4 + r;
        if (n >= NN) continue;
        size_t base = (size_t)n * HID;
#pragma unroll
        for (int ct = 0; ct < 4; ct++) {
            int c = ct * 16 + col;
            xl16[base + c] = (_Float16)d[0][ct][r];
            xr16[base + c] = (_Float16)d[1][ct][r];
            acc[base + c] = d[2][ct][r] + bvec[c] + rb[c];
        }
    }
}

// ---- fused per-dst attention: 32 edges/iter (4 per e-slot) x 8 channels ----
// logit = dot(0.6*att, v) + dot(0.4*att, |v|) in packed fp16 (v_dot2);
// PV via v_dot2 with perm-packed x pairs and fp16 p; exact defer-max.
__global__ __launch_bounds__(256) void k_attn_dst(
        const int* __restrict__ off, const u16* __restrict__ srcs,
        const _Float16* __restrict__ xl16, const _Float16* __restrict__ xr16,
        const _Float16* __restrict__ attL, float* __restrict__ acc) {
    const int lane = threadIdx.x & 63;
    const int d = blockIdx.x * 4 + (threadIdx.x >> 6);
    if (d >= NN) return;
    const int e = lane >> 3;
    const int cg = lane & 7;

    uint4 X = *(const uint4*)&xr16[(size_t)d * HID + 8 * cg];
    uint4 A6 = *(const uint4*)&attL[8 * cg];
    uint4 A4 = *(const uint4*)&attL[HID + 8 * cg];
    h2v xh0 = u2h(X.x), xh1 = u2h(X.y), xh2 = u2h(X.z), xh3 = u2h(X.w);
    h2v a60 = u2h(A6.x), a61 = u2h(A6.y), a62 = u2h(A6.z), a63 = u2h(A6.w);
    h2v a40 = u2h(A4.x), a41 = u2h(A4.y), a42 = u2h(A4.z), a43 = u2h(A4.w);

#define EDGE_LOGIT(S, U, T)                                                    \
    {                                                                          \
        U = *(const uint4*)&xl16[(size_t)(S) * HID + 8 * cg];                  \
        h2v _v; unsigned _a; float _ps;                                        \
        _v = u2h(U.x) + xh0; _a = h2u(_v) & 0x7FFF7FFFu;                       \
        _ps = __builtin_amdgcn_fdot2(a60, _v, 0.f, false);                     \
        _ps = __builtin_amdgcn_fdot2(a40, u2h(_a), _ps, false);                \
        _v = u2h(U.y) + xh1; _a = h2u(_v) & 0x7FFF7FFFu;                       \
        _ps = __builtin_amdgcn_fdot2(a61, _v, _ps, false);                     \
        _ps = __builtin_amdgcn_fdot2(a41, u2h(_a), _ps, false);                \
        _v = u2h(U.z) + xh2; _a = h2u(_v) & 0x7FFF7FFFu;                       \
        _ps = __builtin_amdgcn_fdot2(a62, _v, _ps, false);                     \
        _ps = __builtin_amdgcn_fdot2(a42, u2h(_a), _ps, false);                \
        _v = u2h(U.w) + xh3; _a = h2u(_v) & 0x7FFF7FFFu;                       \
        _ps = __builtin_amdgcn_fdot2(a63, _v, _ps, false);                     \
        _ps = __builtin_amdgcn_fdot2(a43, u2h(_a), _ps, false);                \
        _ps += __shfl_xor(_ps, 1, 64);                                         \
        _ps += __shfl_xor(_ps, 2, 64);                                         \
        _ps += __shfl_xor(_ps, 4, 64);                                         \
        T = _ps;                                                               \
    }

    float m = -INFINITY, l = 0.f;
    float4 oA = make_float4(0.f, 0.f, 0.f, 0.f);
    float4 oB = make_float4(0.f, 0.f, 0.f, 0.f);

    const int lo = off[d], deg = off[d + 1] - lo;   // includes self-loop
    int sv = 0;
    if (lane < 32) sv = (int)srcs[lo + min(lane, deg - 1)];
    for (int base = 0; base < deg; base += 32) {
        int svc = sv;
        if (base + 32 < deg && lane < 32)
            sv = (int)srcs[lo + min(base + 32 + lane, deg - 1)];   // prefetch
        int s0 = __shfl(svc, e, 64);
        int s1 = __shfl(svc, e + 8, 64);
        int s2 = __shfl(svc, e + 16, 64);
        int s3 = __shfl(svc, e + 24, 64);

        uint4 U0, U1, U2, U3; float t0, t1, t2, t3;
        EDGE_LOGIT(s0, U0, t0);
        EDGE_LOGIT(s1, U1, t1);
        EDGE_LOGIT(s2, U2, t2);
        EDGE_LOGIT(s3, U3, t3);
        if (base + e >= deg) t0 = -INFINITY;
        if (base + 8 + e >= deg) t1 = -INFINITY;
        if (base + 16 + e >= deg) t2 = -INFINITY;
        if (base + 24 + e >= deg) t3 = -INFINITY;

        float cm = fmaxf(fmaxf(t0, t1), fmaxf(t2, t3));
        cm = fmaxf(cm, __shfl_xor(cm, 8, 64));
        cm = fmaxf(cm, __shfl_xor(cm, 16, 64));
        cm = fmaxf(cm, __shfl_xor(cm, 32, 64));
        if (cm > m) {                      // wave-uniform; first iter always
            float corr = __expf(m - cm);   // exp(-inf)=0 on first iter
            m = cm;
            l *= corr;
            oA.x *= corr; oA.y *= corr; oA.z *= corr; oA.w *= corr;
            oB.x *= corr; oB.y *= corr; oB.z *= corr; oB.w *= corr;
        }                                  // else corr == 1 exactly: skip
        float p0 = __expf(t0 - m);
        float p1 = __expf(t1 - m);
        float p2 = __expf(t2 - m);
        float p3 = __expf(t3 - m);
        l += (p0 + p1) + (p2 + p3);
        h2v p01 = {(_Float16)p0, (_Float16)p1};
        h2v p23 = {(_Float16)p2, (_Float16)p3};
        oA.x = __builtin_amdgcn_fdot2(p01, pklo(U0.x, U1.x), oA.x, false);
        oA.x = __builtin_amdgcn_fdot2(p23, pklo(U2.x, U3.x), oA.x, false);
        oA.y = __builtin_amdgcn_fdot2(p01, pkhi(U0.x, U1.x), oA.y, false);
        oA.y = __builtin_amdgcn_fdot2(p23, pkhi(U2.x, U3.x), oA.y, false);
        oA.z = __builtin_amdgcn_fdot2(p01, pklo(U0.y, U1.y), oA.z, false);
        oA.z = __builtin_amdgcn_fdot2(p23, pklo(U2.y, U3.y), oA.z, false);
        oA.w = __builtin_amdgcn_fdot2(p01, pkhi(U0.y, U1.y), oA.w, false);
        oA.w = __builtin_amdgcn_fdot2(p23, pkhi(U2.y, U3.y), oA.w, false);
        oB.x = __builtin_amdgcn_fdot2(p01, pklo(U0.z, U1.z), oB.x, false);
        oB.x = __builtin_amdgcn_fdot2(p23, pklo(U2.z, U3.z), oB.x, false);
        oB.y = __builtin_amdgcn_fdot2(p01, pkhi(U0.z, U1.z), oB.y, false);
        oB.y = __builtin_amdgcn_fdot2(p23, pkhi(U2.z, U3.z), oB.y, false);
        oB.z = __builtin_amdgcn_fdot2(p01, pklo(U0.w, U1.w), oB.z, false);
        oB.z = __builtin_amdgcn_fdot2(p23, pklo(U2.w, U3.w), oB.z, false);
        oB.w = __builtin_amdgcn_fdot2(p01, pkhi(U0.w, U1.w), oB.w, false);
        oB.w = __builtin_amdgcn_fdot2(p23, pkhi(U2.w, U3.w), oB.w, false);
    }
#undef EDGE_LOGIT

#pragma unroll
    for (int w = 8; w <= 32; w <<= 1) {
        l    += __shfl_xor(l, w, 64);
        oA.x += __shfl_xor(oA.x, w, 64); oA.y += __shfl_xor(oA.y, w, 64);
        oA.z += __shfl_xor(oA.z, w, 64); oA.w += __shfl_xor(oA.w, w, 64);
        oB.x += __shfl_xor(oB.x, w, 64); oB.y += __shfl_xor(oB.y, w, 64);
        oB.z += __shfl_xor(oB.z, w, 64); oB.w += __shfl_xor(oB.w, w, 64);
    }

    if (e == 0) {
        float inv = 1.f / l;
        float4* a4 = (float4*)&acc[(size_t)d * HID + 8 * cg];
        float4 c0 = a4[0], c1 = a4[1];
        c0.x += oA.x * inv; c0.y += oA.y * inv;
        c0.z += oA.z * inv; c0.w += oA.w * inv;
        c1.x += oB.x * inv; c1.y += oB.y * inv;
        c1.z += oB.z * inv; c1.w += oB.w * inv;
        a4[0] = c0; a4[1] = c1;
    }
}

// ---- fused mean-pool + head ----
__global__ __launch_bounds__(512) void k_pool_final(
        const float* __restrict__ acc,
        const int* __restrict__ startg, const int* __restrict__ endg,
        const float* __restrict__ Wf, const float* __restrict__ bf_,
        float* __restrict__ out) {
    __shared__ float red[8][HID];
    const int g = blockIdx.x;
    const int c = threadIdx.x & 63;
    const int j = threadIdx.x >> 6;
    const int s = startg[g], epos = endg[g];

    float sum = 0.f;
    for (int n = s + j; n < epos; n += 8)
        sum += acc[(size_t)n * HID + c];
    red[j][c] = sum;
    __syncthreads();

    if (threadIdx.x < HID) {
        float tot = 0.f;
#pragma unroll
        for (int w = 0; w < 8; w++) tot += red[w][c];
        float cntf = (float)(epos - s);
        float v = tot / fmaxf(cntf, 1.f) * Wf[c];
#pragma unroll
        for (int o = 32; o; o >>= 1) v += __shfl_xor(v, o, 64);
        if (c == 0) out[g] = v + bf_[0];
    }
}

extern "C" void kernel_launch(void* const* d_in, const int* in_sizes, int n_in,
                              void* d_out, int out_size, void* d_ws, size_t ws_size,
                              hipStream_t stream) {
    const float* x   = (const float*)d_in[0];
    const int* eidx  = (const int*)d_in[1];
    const int* batch = (const int*)d_in[2];
    const int* esrc = eidx;
    const int* edst = eidx + NE;
    const float* Wf  = (const float*)d_in[21];
    const float* bfb = (const float*)d_in[22];

    float* wsf = (float*)d_ws;
    const size_t NN64 = (size_t)NN * HID;
    _Float16* xl16 = (_Float16*)wsf;                // NN64 halfs (slot: NN64 floats)
    _Float16* xr16 = (_Float16*)(wsf + NN64);       // NN64 halfs
    float* acc0   = wsf + 2 * NN64;
    float* acc1   = acc0 + NN64;
    short* Ws0    = (short*)(acc1 + NN64);
    short* Ws1    = Ws0 + 2 * 3 * HID * DIN0;
    short* Ws2    = Ws1 + 2 * 3 * HID * HID;
    int*   ccnt   = (int*)(Ws2 + 2 * 3 * HID * HID);
    int*   startg = ccnt + NN;
    int*   endg   = startg + NG;
    int*   off    = endg + NG;
    int*   part   = off + NN + 1;
    int*   partSc = part + SNB;
    int*   cnt8   = partSc + SNB;                   // 8*NN
    u16*   rank   = (u16*)(cnt8 + 8 * NN);          // NE u16
    u16*   srcs   = rank + NE;                      // NE + NN u16 (self-loops)
    _Float16* attp = (_Float16*)(srcs + NE + NN);   // 3 * 2*HID halfs

    k_wt_all<<<(3 * HID * DIN0 + 2 * 3 * HID * HID + 255) / 256, 256, 0, stream>>>(
        (const float*)d_in[3], (const float*)d_in[4], (const float*)d_in[7],
        (const float*)d_in[9], (const float*)d_in[10], (const float*)d_in[13],
        (const float*)d_in[15], (const float*)d_in[16], (const float*)d_in[19],
        (const float*)d_in[5], (const float*)d_in[11], (const float*)d_in[17],
        Ws0, Ws1, Ws2, attp, startg, endg);
    k_bounds<<<(NN + 255) / 256, 256, 0, stream>>>(batch, startg, endg, cnt8);

    k_hist8<<<512, 256, 0, stream>>>(edst, cnt8, rank);
    k_hist_red<<<(NN + 255) / 256, 256, 0, stream>>>(cnt8, ccnt);
    k_scan_part<<<SNB, 256, 0, stream>>>(ccnt, part);
    k_scan_small<<<1, 64, 0, stream>>>(part, partSc);
    k_scan_emit<<<SNB, 256, 0, stream>>>(ccnt, partSc, off, srcs);
    k_scatter_rank<<<(NE + 255) / 256, 256, 0, stream>>>(esrc, edst, off, cnt8, rank, srcs);

    const short* Wss[3] = {Ws0, Ws1, Ws2};
    float* accs[4] = {acc0, acc0, acc1, acc0};  // out of layer L = accs[L+1]
    const int gemm_grid = (NN + 63) / 64;
    for (int L = 0; L < 3; L++) {
        const float* b   = (const float*)d_in[3 + L * 6 + 3];
        const float* Rb  = (const float*)d_in[3 + L * 6 + 5];
        float* accOut = accs[L + 1];

        if (L == 0)
            k_gemm<DIN0, false><<<gemm_grid, 256, 0, stream>>>(
                x, Wss[0], b, Rb, xl16, xr16, accOut);
        else
            k_gemm<HID, true><<<gemm_grid, 256, 0, stream>>>(
                accs[L], Wss[L], b, Rb, xl16, xr16, accOut);

        k_attn_dst<<<(NN + 3) / 4, 256, 0, stream>>>(
            off, srcs, xl16, xr16, attp + L * 2 * HID, accOut);
    }

    k_pool_final<<<NG, 512, 0, stream>>>(accs[3], startg, endg, Wf, bfb, (float*)d_out);
}

// Round 3
// 347.326 us; speedup vs baseline: 1.0809x; 1.0011x over previous
//
#include <hip/hip_runtime.h>

// GATv2 3-layer + mean-pool + linear head, MI355X.
// R22: attn latency/waste diet. (1) srcs distributed by direct per-lane u16
// loads (L1 broadcast across the 8 lanes of an e-slot) instead of staged
// load + 4x ds_bpermute - removes the LGKM chain at the top of each chunk.
// (2) wave-uniform slot skip: deg is uniform per wave, so slots 2/3
// (logit + exp + PV dots) only run when rem>16 / rem>24 - saves ~1 slot of
// work for ~95% of dsts (deg ~ Poisson(20)+1). (3) xor-32 reduce level via
// v_permlane32_swap (VALU) instead of ds_bpermute. R21's fp16 dot2 logits/PV,
// self-loop-in-CSR, exact defer-max all kept.

#define NN 50000
#define NE 1000000
#define HID 64
#define DIN0 128
#define NG 256
#define NEG 0.2f

#define SCHUNK 1024
#define SNB ((NN + SCHUNK - 1) / SCHUNK)   // 49 blocks

typedef float f32x4 __attribute__((ext_vector_type(4)));
typedef short s8v __attribute__((ext_vector_type(8)));
typedef short s4v __attribute__((ext_vector_type(4)));
typedef __bf16 bf16x8 __attribute__((ext_vector_type(8)));
typedef _Float16 h2v __attribute__((ext_vector_type(2)));
typedef unsigned u32x2 __attribute__((ext_vector_type(2)));
typedef unsigned short u16;

__device__ __forceinline__ unsigned short f2bf(float f) {
    unsigned u = __float_as_uint(f);
    u = u + 0x7fffu + ((u >> 16) & 1u);   // RNE
    return (unsigned short)(u >> 16);
}
__device__ __forceinline__ float bf2f(unsigned short v) {
    return __uint_as_float(((unsigned)v) << 16);
}
__device__ __forceinline__ short split_hi(float x) {
    return (short)f2bf(x);
}
__device__ __forceinline__ short split_lo(float x, short hi) {
    return (short)f2bf(x - bf2f((unsigned short)hi));
}
__device__ __forceinline__ h2v u2h(unsigned u) { return __builtin_bit_cast(h2v, u); }
__device__ __forceinline__ unsigned h2u(h2v h) { return __builtin_bit_cast(unsigned, h); }
// (b.lo16 << 16) | a.lo16  and  (b.hi16 << 16) | a.hi16  - one v_perm_b32 each
__device__ __forceinline__ h2v pklo(unsigned a, unsigned b) {
    return u2h(__builtin_amdgcn_perm(b, a, 0x05040100u));
}
__device__ __forceinline__ h2v pkhi(unsigned a, unsigned b) {
    return u2h(__builtin_amdgcn_perm(b, a, 0x07060302u));
}
// cross-half (lane ^ 32) reduce via v_permlane32_swap: one VALU op yields both
// halves; r0[i]+r1[i] = v[i&31] + v[(i&31)+32] for all lanes.
__device__ __forceinline__ float red32_add(float v) {
    unsigned u = __float_as_uint(v);
    u32x2 r = __builtin_amdgcn_permlane32_swap(u, u, false, false);
    return __uint_as_float(r[0]) + __uint_as_float(r[1]);
}
__device__ __forceinline__ float red32_max(float v) {
    unsigned u = __float_as_uint(v);
    u32x2 r = __builtin_amdgcn_permlane32_swap(u, u, false, false);
    return fmaxf(__uint_as_float(r[0]), __uint_as_float(r[1]));
}

// ---- merged weight pre-split (all 3 layers) + att fp16 tables + zero bounds ----
__global__ __launch_bounds__(256) void k_wt_all(
        const float* __restrict__ Wl0, const float* __restrict__ Wr0, const float* __restrict__ Rw0,
        const float* __restrict__ Wl1, const float* __restrict__ Wr1, const float* __restrict__ Rw1,
        const float* __restrict__ Wl2, const float* __restrict__ Wr2, const float* __restrict__ Rw2,
        const float* __restrict__ att0, const float* __restrict__ att1, const float* __restrict__ att2,
        short* __restrict__ Ws0, short* __restrict__ Ws1, short* __restrict__ Ws2,
        _Float16* __restrict__ attp,
        int* __restrict__ startg, int* __restrict__ endg) {
    int i = blockIdx.x * 256 + threadIdx.x;
    if (i < 2 * NG) {
        if (i < NG) startg[i] = 0; else endg[i - NG] = 0;
    }
    if (i < 3 * HID) {   // leaky(v)*a = 0.6a*v + 0.4a*|v|; pre-scale in fp16
        int L = i >> 6, c = i & 63;
        const float* at = (L == 0) ? att0 : (L == 1) ? att1 : att2;
        float a = at[c];
        attp[L * 2 * HID + c] = (_Float16)(0.6f * a);
        attp[L * 2 * HID + HID + c] = (_Float16)(0.4f * a);
    }
    const int L0N = 3 * HID * DIN0;
    const int L1N = 3 * HID * HID;
    if (i >= L0N + 2 * L1N) return;
    const float* Wm; short* Ws; int din, local;
    if (i < L0N) {
        local = i; din = DIN0; Ws = Ws0;
        int m = local / (DIN0 * HID);
        Wm = (m == 0) ? Wl0 : (m == 1) ? Wr0 : Rw0;
    } else if (i < L0N + L1N) {
        local = i - L0N; din = HID; Ws = Ws1;
        int m = local / (HID * HID);
        Wm = (m == 0) ? Wl1 : (m == 1) ? Wr1 : Rw1;
    } else {
        local = i - L0N - L1N; din = HID; Ws = Ws2;
        int m = local / (HID * HID);
        Wm = (m == 0) ? Wl2 : (m == 1) ? Wr2 : Rw2;
    }
    int m = local / (din * HID);
    int r = local - m * (din * HID);
    int c = r / din, k = r - c * din;
    float w = Wm[c * din + k];
    short hi = split_hi(w);
    short lo = split_lo(w, hi);
    Ws[(((m * 2 + 0) * HID + c) * din) + k] = hi;
    Ws[(((m * 2 + 1) * HID + c) * din) + k] = lo;
}

// ---- graph bounds + zero hist slices ----
__global__ void k_bounds(const int* __restrict__ batch,
                         int* __restrict__ startg, int* __restrict__ endg,
                         int* __restrict__ cnt8) {
    int i = blockIdx.x * 256 + threadIdx.x;
    if (i >= NN) return;
#pragma unroll
    for (int g = 0; g < 8; g++) cnt8[g * NN + i] = 0;
    int g = batch[i];
    if (i == 0 || batch[i - 1] != g) startg[g] = i;
    if (i == NN - 1 || batch[i + 1] != g) endg[g] = i + 1;
}

// ---- XCD-sliced histogram; atomic return = rank within (slice,dst) ----
__global__ __launch_bounds__(256) void k_hist8(const int* __restrict__ edst,
                                               int* __restrict__ cnt8,
                                               u16* __restrict__ rank) {
    int* mycnt = cnt8 + (blockIdx.x & 7) * NN;
    for (int e = blockIdx.x * 256 + threadIdx.x; e < NE; e += 512 * 256) {
        int r = atomicAdd(&mycnt[edst[e]], 1);
        rank[e] = (u16)r;
    }
}

// ---- per-dst: slice-exclusive prefixes (in place) + total ----
// prefixes start at 1 - slot 0 of each dst is the self-loop edge.
__global__ void k_hist_red(int* __restrict__ cnt8, int* __restrict__ cnt) {
    int i = blockIdx.x * 256 + threadIdx.x;
    if (i >= NN) return;
    int s = 1;                               // reserve slot 0 for self-loop
#pragma unroll
    for (int g = 0; g < 8; g++) {
        int t = cnt8[g * NN + i];
        cnt8[g * NN + i] = s;
        s += t;
    }
    cnt[i] = s;                              // deg + 1 (incl self)
}

__global__ __launch_bounds__(256) void k_scan_part(const int* __restrict__ cnt,
                                                   int* __restrict__ part) {
    __shared__ int ws[4];
    int b = blockIdx.x, t = threadIdx.x;
    int i0 = b * SCHUNK + t * 4;
    int s = 0;
#pragma unroll
    for (int j = 0; j < 4; j++) {
        int i = i0 + j;
        if (i < NN) s += cnt[i];
    }
#pragma unroll
    for (int o = 32; o; o >>= 1) s += __shfl_xor(s, o, 64);
    if ((t & 63) == 0) ws[t >> 6] = s;
    __syncthreads();
    if (t == 0) part[b] = ws[0] + ws[1] + ws[2] + ws[3];
}

__global__ void k_scan_small(const int* __restrict__ part, int* __restrict__ partScan) {
    __shared__ int sh[SNB];
    int t = threadIdx.x;
    if (t < SNB) sh[t] = part[t];
    __syncthreads();
    if (t < SNB) {
        int s = 0;
        for (int i = 0; i < t; i++) s += sh[i];
        partScan[t] = s;
    }
}

// also writes the self-loop src (srcs[off[i]] = i) - runs before scatter.
__global__ __launch_bounds__(256) void k_scan_emit(const int* __restrict__ cnt,
                                                   const int* __restrict__ partScan,
                                                   int* __restrict__ off,
                                                   u16* __restrict__ srcs) {
    __shared__ int tsum[256];
    int b = blockIdx.x, t = threadIdx.x;
    int i0 = b * SCHUNK + t * 4;
    int e[4], p[4];
    int s = 0;
#pragma unroll
    for (int j = 0; j < 4; j++) {
        int i = i0 + j;
        e[j] = (i < NN) ? cnt[i] : 0;
        p[j] = s;
        s += e[j];
    }
    tsum[t] = s;
    __syncthreads();
    for (int d = 1; d < 256; d <<= 1) {
        int v = (t >= d) ? tsum[t - d] : 0;
        __syncthreads();
        tsum[t] += v;
        __syncthreads();
    }
    int base = partScan[b] + ((t == 0) ? 0 : tsum[t - 1]);
#pragma unroll
    for (int j = 0; j < 4; j++) {
        int i = i0 + j;
        if (i < NN) {
            int v = base + p[j];
            off[i] = v;
            srcs[v] = (u16)i;                // self-loop edge in slot 0
            if (i == NN - 1) off[NN] = v + e[j];
        }
    }
}

// ---- atomic-free scatter: pos = off[d] + sliceBase[slice][d] + rank[e] ----
__global__ __launch_bounds__(256) void k_scatter_rank(
        const int* __restrict__ esrc, const int* __restrict__ edst,
        const int* __restrict__ off, const int* __restrict__ cnt8,
        const u16* __restrict__ rank, u16* __restrict__ srcs) {
    int e = blockIdx.x * 256 + threadIdx.x;
    if (e >= NE) return;
    int d = edst[e];
    int slice = (e >> 8) & 7;               // matches k_hist8's block mapping
    int pos = off[d] + cnt8[slice * NN + d] + (int)rank[e];
    srcs[pos] = (u16)esrc[e];
}

// ---- fused node GEMMs via split-precision bf16 MFMA; xl,xr output as fp16 ----
template <int DIN, bool RELU>
__global__ __launch_bounds__(256, 3) void k_gemm(
        const float* __restrict__ xin, const short* __restrict__ Ws,
        const float* __restrict__ bvec, const float* __restrict__ rb,
        _Float16* __restrict__ xl16, _Float16* __restrict__ xr16, float* __restrict__ acc) {
    constexpr int LROW = 40;
    __shared__ short lds[20480];            // 40 KB
    short* xhi = lds;
    short* xlo = lds + 2560;

    const int tid = threadIdx.x;
    const int w = tid >> 6;
    const int lane = tid & 63;
    const int col = lane & 15;
    const int quad = lane >> 4;
    const int nb0 = blockIdx.x * 64;

    f32x4 d[3][4];
#pragma unroll
    for (int m = 0; m < 3; m++)
#pragma unroll
        for (int ct = 0; ct < 4; ct++) d[m][ct] = (f32x4){0.f, 0.f, 0.f, 0.f};

    for (int c0 = 0; c0 < DIN; c0 += 32) {
        if (c0) __syncthreads();
        for (int u = tid; u < 512; u += 256) {
            int row = u >> 3, kq = u & 7;
            int n = nb0 + row;
            float4 v = make_float4(0.f, 0.f, 0.f, 0.f);
            if (n < NN) {
                v = *(const float4*)&xin[(size_t)n * DIN + c0 + 4 * kq];
                if (RELU) {
                    v.x = fmaxf(v.x, 0.f); v.y = fmaxf(v.y, 0.f);
                    v.z = fmaxf(v.z, 0.f); v.w = fmaxf(v.w, 0.f);
                }
            }
            s4v h, l;
            short h0 = split_hi(v.x), l0 = split_lo(v.x, h0);
            short h1 = split_hi(v.y), l1 = split_lo(v.y, h1);
            short h2 = split_hi(v.z), l2 = split_lo(v.z, h2);
            short h3 = split_hi(v.w), l3 = split_lo(v.w, h3);
            h[0] = h0; h[1] = h1; h[2] = h2; h[3] = h3;
            l[0] = l0; l[1] = l1; l[2] = l2; l[3] = l3;
            *(s4v*)&xhi[row * LROW + 4 * kq] = h;
            *(s4v*)&xlo[row * LROW + 4 * kq] = l;
        }
        for (int u = tid; u < 1536; u += 256) {
            int mp = u >> 8;
            int r = u & 255;
            int c = r >> 2, q = r & 3;
            s8v v = *(const s8v*)&Ws[((mp * HID + c) * DIN) + c0 + 8 * q];
            *(s8v*)&lds[5120 + mp * 2560 + c * LROW + 8 * q] = v;
        }
        __syncthreads();

        bf16x8 a_h = __builtin_bit_cast(bf16x8,
            *(const s8v*)&xhi[(w * 16 + col) * LROW + quad * 8]);
        bf16x8 a_l = __builtin_bit_cast(bf16x8,
            *(const s8v*)&xlo[(w * 16 + col) * LROW + quad * 8]);

#pragma unroll
        for (int m = 0; m < 3; m++) {
#pragma unroll
            for (int ct = 0; ct < 4; ct++) {
                bf16x8 b_h = __builtin_bit_cast(bf16x8,
                    *(const s8v*)&lds[5120 + (m * 2 + 0) * 2560 + (ct * 16 + col) * LROW + quad * 8]);
                bf16x8 b_l = __builtin_bit_cast(bf16x8,
                    *(const s8v*)&lds[5120 + (m * 2 + 1) * 2560 + (ct * 16 + col) * LROW + quad * 8]);
                d[m][ct] = __builtin_amdgcn_mfma_f32_16x16x32_bf16(a_h, b_h, d[m][ct], 0, 0, 0);
                d[m][ct] = __builtin_amdgcn_mfma_f32_16x16x32_bf16(a_h, b_l, d[m][ct], 0, 0, 0);
                d[m][ct] = __builtin_amdgcn_mfma_f32_16x16x32_bf16(a_l, b_h, d[m][ct], 0, 0, 0);
            }
        }
    }

#pragma unroll
    for (int r = 0; r < 4; r++) {
        int n = nb0 + w * 16 + quad * 4 + r;
        if (n >= NN) continue;
        size_t base = (size_t)n * HID;
#pragma unroll
        for (int ct = 0; ct < 4; ct++) {
            int c = ct * 16 + col;
            xl16[base + c] = (_Float16)d[0][ct][r];
            xr16[base + c] = (_Float16)d[1][ct][r];
            acc[base + c] = d[2][ct][r] + bvec[c] + rb[c];
        }
    }
}

// ---- fused per-dst attention: 32 edges/iter (4 per e-slot) x 8 channels ----
// logit = dot(0.6*att, v) + dot(0.4*att, |v|) in packed fp16 (v_dot2);
// PV via v_dot2 with perm-packed x pairs and fp16 p; exact defer-max;
// direct per-lane srcs loads; wave-uniform slot 2/3 skip.
__global__ __launch_bounds__(256) void k_attn_dst(
        const int* __restrict__ off, const u16* __restrict__ srcs,
        const _Float16* __restrict__ xl16, const _Float16* __restrict__ xr16,
        const _Float16* __restrict__ attL, float* __restrict__ acc) {
    const int lane = threadIdx.x & 63;
    const int d = blockIdx.x * 4 + (threadIdx.x >> 6);
    if (d >= NN) return;
    const int e = lane >> 3;
    const int cg = lane & 7;

    const int lo = off[d], deg = off[d + 1] - lo;   // includes self-loop

    uint4 X = *(const uint4*)&xr16[(size_t)d * HID + 8 * cg];
    uint4 A6 = *(const uint4*)&attL[8 * cg];
    uint4 A4 = *(const uint4*)&attL[HID + 8 * cg];
    h2v xh0 = u2h(X.x), xh1 = u2h(X.y), xh2 = u2h(X.z), xh3 = u2h(X.w);
    h2v a60 = u2h(A6.x), a61 = u2h(A6.y), a62 = u2h(A6.z), a63 = u2h(A6.w);
    h2v a40 = u2h(A4.x), a41 = u2h(A4.y), a42 = u2h(A4.z), a43 = u2h(A4.w);

#define EDGE_LOGIT(S, U, T)                                                    \
    {                                                                          \
        U = *(const uint4*)&xl16[(size_t)(S) * HID + 8 * cg];                  \
        h2v _v; unsigned _a; float _ps;                                        \
        _v = u2h(U.x) + xh0; _a = h2u(_v) & 0x7FFF7FFFu;                       \
        _ps = __builtin_amdgcn_fdot2(a60, _v, 0.f, false);                     \
        _ps = __builtin_amdgcn_fdot2(a40, u2h(_a), _ps, false);                \
        _v = u2h(U.y) + xh1; _a = h2u(_v) & 0x7FFF7FFFu;                       \
        _ps = __builtin_amdgcn_fdot2(a61, _v, _ps, false);                     \
        _ps = __builtin_amdgcn_fdot2(a41, u2h(_a), _ps, false);                \
        _v = u2h(U.z) + xh2; _a = h2u(_v) & 0x7FFF7FFFu;                       \
        _ps = __builtin_amdgcn_fdot2(a62, _v, _ps, false);                     \
        _ps = __builtin_amdgcn_fdot2(a42, u2h(_a), _ps, false);                \
        _v = u2h(U.w) + xh3; _a = h2u(_v) & 0x7FFF7FFFu;                       \
        _ps = __builtin_amdgcn_fdot2(a63, _v, _ps, false);                     \
        _ps = __builtin_amdgcn_fdot2(a43, u2h(_a), _ps, false);                \
        _ps += __shfl_xor(_ps, 1, 64);                                         \
        _ps += __shfl_xor(_ps, 2, 64);                                         \
        _ps += __shfl_xor(_ps, 4, 64);                                         \
        T = _ps;                                                               \
    }

    float m = -INFINITY, l = 0.f;
    float4 oA = make_float4(0.f, 0.f, 0.f, 0.f);
    float4 oB = make_float4(0.f, 0.f, 0.f, 0.f);

    for (int base = 0; base < deg; base += 32) {
        const int rem = deg - base;                 // wave-uniform
        int s0 = (int)srcs[lo + min(base + e, deg - 1)];
        int s1 = (int)srcs[lo + min(base + 8 + e, deg - 1)];

        uint4 U0, U1, U2, U3;
        float t0, t1, t2 = -INFINITY, t3 = -INFINITY;
        EDGE_LOGIT(s0, U0, t0);
        EDGE_LOGIT(s1, U1, t1);
        if (base + e >= deg) t0 = -INFINITY;
        if (base + 8 + e >= deg) t1 = -INFINITY;

        const bool do2 = rem > 16;                  // wave-uniform branches
        if (do2) {
            int s2 = (int)srcs[lo + min(base + 16 + e, deg - 1)];
            EDGE_LOGIT(s2, U2, t2);
            if (base + 16 + e >= deg) t2 = -INFINITY;
            if (rem > 24) {
                int s3 = (int)srcs[lo + min(base + 24 + e, deg - 1)];
                EDGE_LOGIT(s3, U3, t3);
                if (base + 24 + e >= deg) t3 = -INFINITY;
            } else {
                U3 = U0;                            // valid bits; p3 will be 0
            }
        }

        float cm = fmaxf(fmaxf(t0, t1), fmaxf(t2, t3));
        cm = fmaxf(cm, __shfl_xor(cm, 8, 64));
        cm = fmaxf(cm, __shfl_xor(cm, 16, 64));
        cm = red32_max(cm);
        if (cm > m) {                      // wave-uniform; first iter always
            float corr = __expf(m - cm);   // exp(-inf)=0 on first iter
            m = cm;
            l *= corr;
            oA.x *= corr; oA.y *= corr; oA.z *= corr; oA.w *= corr;
            oB.x *= corr; oB.y *= corr; oB.z *= corr; oB.w *= corr;
        }                                  // else corr == 1 exactly: skip
        float p0 = __expf(t0 - m);
        float p1 = __expf(t1 - m);
        l += p0 + p1;
        h2v p01 = {(_Float16)p0, (_Float16)p1};
        oA.x = __builtin_amdgcn_fdot2(p01, pklo(U0.x, U1.x), oA.x, false);
        oA.y = __builtin_amdgcn_fdot2(p01, pkhi(U0.x, U1.x), oA.y, false);
        oA.z = __builtin_amdgcn_fdot2(p01, pklo(U0.y, U1.y), oA.z, false);
        oA.w = __builtin_amdgcn_fdot2(p01, pkhi(U0.y, U1.y), oA.w, false);
        oB.x = __builtin_amdgcn_fdot2(p01, pklo(U0.z, U1.z), oB.x, false);
        oB.y = __builtin_amdgcn_fdot2(p01, pkhi(U0.z, U1.z), oB.y, false);
        oB.z = __builtin_amdgcn_fdot2(p01, pklo(U0.w, U1.w), oB.z, false);
        oB.w = __builtin_amdgcn_fdot2(p01, pkhi(U0.w, U1.w), oB.w, false);
        if (do2) {
            float p2 = __expf(t2 - m);
            float p3 = __expf(t3 - m);
            l += p2 + p3;
            h2v p23 = {(_Float16)p2, (_Float16)p3};
            oA.x = __builtin_amdgcn_fdot2(p23, pklo(U2.x, U3.x), oA.x, false);
            oA.y = __builtin_amdgcn_fdot2(p23, pkhi(U2.x, U3.x), oA.y, false);
            oA.z = __builtin_amdgcn_fdot2(p23, pklo(U2.y, U3.y), oA.z, false);
            oA.w = __builtin_amdgcn_fdot2(p23, pkhi(U2.y, U3.y), oA.w, false);
            oB.x = __builtin_amdgcn_fdot2(p23, pklo(U2.z, U3.z), oB.x, false);
            oB.y = __builtin_amdgcn_fdot2(p23, pkhi(U2.z, U3.z), oB.y, false);
            oB.z = __builtin_amdgcn_fdot2(p23, pklo(U2.w, U3.w), oB.z, false);
            oB.w = __builtin_amdgcn_fdot2(p23, pkhi(U2.w, U3.w), oB.w, false);
        }
    }
#undef EDGE_LOGIT

#pragma unroll
    for (int w = 8; w <= 16; w <<= 1) {
        l    += __shfl_xor(l, w, 64);
        oA.x += __shfl_xor(oA.x, w, 64); oA.y += __shfl_xor(oA.y, w, 64);
        oA.z += __shfl_xor(oA.z, w, 64); oA.w += __shfl_xor(oA.w, w, 64);
        oB.x += __shfl_xor(oB.x, w, 64); oB.y += __shfl_xor(oB.y, w, 64);
        oB.z += __shfl_xor(oB.z, w, 64); oB.w += __shfl_xor(oB.w, w, 64);
    }
    l    = red32_add(l);
    oA.x = red32_add(oA.x); oA.y = red32_add(oA.y);
    oA.z = red32_add(oA.z); oA.w = red32_add(oA.w);
    oB.x = red32_add(oB.x); oB.y = red32_add(oB.y);
    oB.z = red32_add(oB.z); oB.w = red32_add(oB.w);

    if (e == 0) {
        float inv = 1.f / l;
        float4* a4 = (float4*)&acc[(size_t)d * HID + 8 * cg];
        float4 c0 = a4[0], c1 = a4[1];
        c0.x += oA.x * inv; c0.y += oA.y * inv;
        c0.z += oA.z * inv; c0.w += oA.w * inv;
        c1.x += oB.x * inv; c1.y += oB.y * inv;
        c1.z += oB.z * inv; c1.w += oB.w * inv;
        a4[0] = c0; a4[1] = c1;
    }
}

// ---- fused mean-pool + head ----
__global__ __launch_bounds__(512) void k_pool_final(
        const float* __restrict__ acc,
        const int* __restrict__ startg, const int* __restrict__ endg,
        const float* __restrict__ Wf, const float* __restrict__ bf_,
        float* __restrict__ out) {
    __shared__ float red[8][HID];
    const int g = blockIdx.x;
    const int c = threadIdx.x & 63;
    const int j = threadIdx.x >> 6;
    const int s = startg[g], epos = endg[g];

    float sum = 0.f;
    for (int n = s + j; n < epos; n += 8)
        sum += acc[(size_t)n * HID + c];
    red[j][c] = sum;
    __syncthreads();

    if (threadIdx.x < HID) {
        float tot = 0.f;
#pragma unroll
        for (int w = 0; w < 8; w++) tot += red[w][c];
        float cntf = (float)(epos - s);
        float v = tot / fmaxf(cntf, 1.f) * Wf[c];
#pragma unroll
        for (int o = 32; o; o >>= 1) v += __shfl_xor(v, o, 64);
        if (c == 0) out[g] = v + bf_[0];
    }
}

extern "C" void kernel_launch(void* const* d_in, const int* in_sizes, int n_in,
                              void* d_out, int out_size, void* d_ws, size_t ws_size,
                              hipStream_t stream) {
    const float* x   = (const float*)d_in[0];
    const int* eidx  = (const int*)d_in[1];
    const int* batch = (const int*)d_in[2];
    const int* esrc = eidx;
    const int* edst = eidx + NE;
    const float* Wf  = (const float*)d_in[21];
    const float* bfb = (const float*)d_in[22];

    float* wsf = (float*)d_ws;
    const size_t NN64 = (size_t)NN * HID;
    _Float16* xl16 = (_Float16*)wsf;                // NN64 halfs (slot: NN64 floats)
    _Float16* xr16 = (_Float16*)(wsf + NN64);       // NN64 halfs
    float* acc0   = wsf + 2 * NN64;
    float* acc1   = acc0 + NN64;
    short* Ws0    = (short*)(acc1 + NN64);
    short* Ws1    = Ws0 + 2 * 3 * HID * DIN0;
    short* Ws2    = Ws1 + 2 * 3 * HID * HID;
    int*   ccnt   = (int*)(Ws2 + 2 * 3 * HID * HID);
    int*   startg = ccnt + NN;
    int*   endg   = startg + NG;
    int*   off    = endg + NG;
    int*   part   = off + NN + 1;
    int*   partSc = part + SNB;
    int*   cnt8   = partSc + SNB;                   // 8*NN
    u16*   rank   = (u16*)(cnt8 + 8 * NN);          // NE u16
    u16*   srcs   = rank + NE;                      // NE + NN u16 (self-loops)
    _Float16* attp = (_Float16*)(srcs + NE + NN);   // 3 * 2*HID halfs

    k_wt_all<<<(3 * HID * DIN0 + 2 * 3 * HID * HID + 255) / 256, 256, 0, stream>>>(
        (const float*)d_in[3], (const float*)d_in[4], (const float*)d_in[7],
        (const float*)d_in[9], (const float*)d_in[10], (const float*)d_in[13],
        (const float*)d_in[15], (const float*)d_in[16], (const float*)d_in[19],
        (const float*)d_in[5], (const float*)d_in[11], (const float*)d_in[17],
        Ws0, Ws1, Ws2, attp, startg, endg);
    k_bounds<<<(NN + 255) / 256, 256, 0, stream>>>(batch, startg, endg, cnt8);

    k_hist8<<<512, 256, 0, stream>>>(edst, cnt8, rank);
    k_hist_red<<<(NN + 255) / 256, 256, 0, stream>>>(cnt8, ccnt);
    k_scan_part<<<SNB, 256, 0, stream>>>(ccnt, part);
    k_scan_small<<<1, 64, 0, stream>>>(part, partSc);
    k_scan_emit<<<SNB, 256, 0, stream>>>(ccnt, partSc, off, srcs);
    k_scatter_rank<<<(NE + 255) / 256, 256, 0, stream>>>(esrc, edst, off, cnt8, rank, srcs);

    const short* Wss[3] = {Ws0, Ws1, Ws2};
    float* accs[4] = {acc0, acc0, acc1, acc0};  // out of layer L = accs[L+1]
    const int gemm_grid = (NN + 63) / 64;
    for (int L = 0; L < 3; L++) {
        const float* b   = (const float*)d_in[3 + L * 6 + 3];
        const float* Rb  = (const float*)d_in[3 + L * 6 + 5];
        float* accOut = accs[L + 1];

        if (L == 0)
            k_gemm<DIN0, false><<<gemm_grid, 256, 0, stream>>>(
                x, Wss[0], b, Rb, xl16, xr16, accOut);
        else
            k_gemm<HID, true><<<gemm_grid, 256, 0, stream>>>(
                accs[L], Wss[L], b, Rb, xl16, xr16, accOut);

        k_attn_dst<<<(NN + 3) / 4, 256, 0, stream>>>(
            off, srcs, xl16, xr16, attp + L * 2 * HID, accOut);
    }

    k_pool_final<<<NG, 512, 0, stream>>>(accs[3], startg, endg, Wf, bfb, (float*)d_out);
}